// Round 6
// baseline (416.150 us; speedup 1.0000x reference)
//
#include <hip/hip_runtime.h>
#include <hip/hip_bf16.h>
#include <stdint.h>

#define N_NODES 100000
#define N_EDGES 1280000
#define IN_DIM  256
#define OUT_DIM 64
#define NB1     98          // ceil(100000/1024) scan blocks

typedef __attribute__((ext_vector_type(8))) short bf16x8;
typedef __attribute__((ext_vector_type(4))) float f32x4;
typedef __attribute__((ext_vector_type(4))) unsigned short u16x4;

__device__ __forceinline__ unsigned short f32_to_bf16(float f) {
    union { float f; unsigned int u; } c; c.f = f;
    unsigned int u = c.u;
    u += 0x7fffu + ((u >> 16) & 1u);   // RNE
    return (unsigned short)(u >> 16);
}

// ---------------------------------------------------------------------------
// GEMM: pre[N][64] fp32 = bf16(X[N][256]) @ bf16(W[256][64]), MFMA 16x16x32.
// (unchanged from round 5 — proven correct, <91 us)
// ---------------------------------------------------------------------------
__global__ __launch_bounds__(256) void gemm_kernel(const float* __restrict__ x,
                                                   const float* __restrict__ w,
                                                   float* __restrict__ pre) {
    __shared__ __align__(16) unsigned short wt[8 * 4 * 64 * 8];   // 32 KB, B-frag order
    __shared__ __align__(16) unsigned short xs[4][8][4][136];     // 34 KB, A-frag order

    const int tid = threadIdx.x;

    for (int i = tid; i < IN_DIM * OUT_DIM; i += 256) {
        const int k = i >> 6, n = i & 63;
        const int kt = k >> 5, q = (k >> 3) & 3, j = k & 7;
        const int t = n >> 4, l = n & 15;
        wt[((kt * 4 + t) * 64 + q * 16 + l) * 8 + j] = f32_to_bf16(w[i]);
    }

    const int R0 = blockIdx.x * 64;
    #pragma unroll
    for (int it = 0; it < 16; ++it) {
        const int flatv = it * 256 + tid;
        const int r  = flatv >> 6;
        const int k4 = (flatv & 63) * 4;
        int gr = R0 + r; gr = gr < N_NODES ? gr : N_NODES - 1;
        f32x4 xv = *(const f32x4*)(x + (size_t)gr * IN_DIM + k4);
        const int kt = k4 >> 5, q = (k4 >> 3) & 3, j = k4 & 7;
        u16x4 pk;
        pk[0] = f32_to_bf16(xv.x); pk[1] = f32_to_bf16(xv.y);
        pk[2] = f32_to_bf16(xv.z); pk[3] = f32_to_bf16(xv.w);
        *(u16x4*)&xs[r >> 4][kt][q][(r & 15) * 8 + j] = pk;
    }
    __syncthreads();

    const int wave = tid >> 6;
    const int lane = tid & 63;
    const int ln16 = lane & 15;
    const int quad = lane >> 4;

    f32x4 acc[4] = {};

    #pragma unroll
    for (int kt = 0; kt < 8; ++kt) {
        bf16x8 a = *(const bf16x8*)&xs[wave][kt][quad][ln16 * 8];
        #pragma unroll
        for (int t = 0; t < 4; ++t) {
            bf16x8 b = *(const bf16x8*)(&wt[((kt * 4 + t) * 64 + lane) * 8]);
            acc[t] = __builtin_amdgcn_mfma_f32_16x16x32_bf16(a, b, acc[t], 0, 0, 0);
        }
    }

    const int rbase = R0 + wave * 16 + quad * 4;
    #pragma unroll
    for (int t = 0; t < 4; ++t) {
        #pragma unroll
        for (int r = 0; r < 4; ++r) {
            const int rr = rbase + r;
            if (rr < N_NODES)
                pre[(size_t)rr * OUT_DIM + t * 16 + ln16] = acc[t][r];
        }
    }
}

// ---------------------------------------------------------------------------
// Histogram: 8 edges/thread, fire-and-forget atomics (no return -> no wait).
// 625 blocks x 256 threads x 8 = 1,280,000 exactly.
// ---------------------------------------------------------------------------
__global__ __launch_bounds__(256) void hist_kernel(const int* __restrict__ rows,
                                                   int* __restrict__ deg) {
    const int t = blockIdx.x * 256 + threadIdx.x;
    #pragma unroll
    for (int q = 0; q < 8; ++q) {
        atomicAdd(&deg[rows[t + q * 160000]], 1);
    }
}

__global__ __launch_bounds__(256) void scan1_kernel(const int* __restrict__ deg,
                                                    int* __restrict__ off,
                                                    int* __restrict__ bsum) {
    __shared__ int s[256];
    const int t = threadIdx.x;
    const int base = blockIdx.x * 1024 + t * 4;
    int d[4];
    #pragma unroll
    for (int q = 0; q < 4; ++q) {
        const int i = base + q;
        d[q] = i < N_NODES ? deg[i] : 0;
    }
    const int tsum = d[0] + d[1] + d[2] + d[3];
    s[t] = tsum;
    __syncthreads();
    #pragma unroll
    for (int o = 1; o < 256; o <<= 1) {
        const int add = t >= o ? s[t - o] : 0;
        __syncthreads();
        s[t] += add;
        __syncthreads();
    }
    int run = t > 0 ? s[t - 1] : 0;
    #pragma unroll
    for (int q = 0; q < 4; ++q) {
        const int i = base + q;
        if (i < N_NODES) off[i] = run;
        run += d[q];
    }
    if (t == 255) bsum[blockIdx.x] = run;
}

__global__ __launch_bounds__(128) void scan2_kernel(const int* __restrict__ bsum,
                                                    int* __restrict__ boff,
                                                    int* __restrict__ off) {
    __shared__ int s[128];
    const int t = threadIdx.x;
    const int v = t < NB1 ? bsum[t] : 0;
    s[t] = v;
    __syncthreads();
    #pragma unroll
    for (int o = 1; o < 128; o <<= 1) {
        const int add = t >= o ? s[t - o] : 0;
        __syncthreads();
        s[t] += add;
        __syncthreads();
    }
    if (t < NB1) boff[t] = t > 0 ? s[t - 1] : 0;
    if (t == 127) off[N_NODES] = s[127];
}

// scan3 also seeds cursor (replaces the d2d memcpy)
__global__ __launch_bounds__(256) void scan3_kernel(int* __restrict__ off,
                                                    const int* __restrict__ boff,
                                                    int* __restrict__ cursor) {
    const int i = blockIdx.x * 256 + threadIdx.x;
    if (i < N_NODES) {
        const int v = off[i] + boff[i >> 10];
        off[i] = v;
        cursor[i] = v;
    }
}

// ---------------------------------------------------------------------------
// Reorder: 4 edges/thread (stride-separated, coalesced loads), 4 independent
// atomic->store chains per thread for ILP. 1250 blocks x 256 x 4 = 1,280,000.
// ---------------------------------------------------------------------------
__global__ __launch_bounds__(256) void reorder_kernel(const int* __restrict__ rows,
                                                      const int* __restrict__ cols,
                                                      const float* __restrict__ vals,
                                                      int* __restrict__ cursor,
                                                      int2* __restrict__ epack) {
    const int t = blockIdx.x * 256 + threadIdx.x;
    int e[4], r[4], c[4], s[4];
    float v[4];
    #pragma unroll
    for (int q = 0; q < 4; ++q) e[q] = t + q * 320000;
    #pragma unroll
    for (int q = 0; q < 4; ++q) r[q] = rows[e[q]];
    #pragma unroll
    for (int q = 0; q < 4; ++q) c[q] = cols[e[q]];
    #pragma unroll
    for (int q = 0; q < 4; ++q) v[q] = vals[e[q]];
    #pragma unroll
    for (int q = 0; q < 4; ++q) s[q] = atomicAdd(&cursor[r[q]], 1);
    #pragma unroll
    for (int q = 0; q < 4; ++q) epack[s[q]] = make_int2(c[q], __float_as_int(v[q]));
}

// ---------------------------------------------------------------------------
// Gather: one wave per node, lane = dim, 4-deep unroll (4 outstanding
// pre-gathers), fused bias + ReLU. Zero atomics.
// ---------------------------------------------------------------------------
__global__ __launch_bounds__(256) void gather_kernel(const int* __restrict__ off,
                                                     const int2* __restrict__ epack,
                                                     const float* __restrict__ pre,
                                                     const float* __restrict__ bias,
                                                     float* __restrict__ out) {
    const int v = blockIdx.x * 4 + (threadIdx.x >> 6);
    const int j = threadIdx.x & 63;
    if (v >= N_NODES) return;
    const int s = off[v];
    const int e = off[v + 1];
    float acc = 0.0f;
    int i = s;
    for (; i + 4 <= e; i += 4) {
        int2 ee[4];
        float p[4];
        #pragma unroll
        for (int q = 0; q < 4; ++q) ee[q] = epack[i + q];
        #pragma unroll
        for (int q = 0; q < 4; ++q) p[q] = pre[(size_t)ee[q].x * OUT_DIM + j];
        #pragma unroll
        for (int q = 0; q < 4; ++q) acc = fmaf(p[q], __int_as_float(ee[q].y), acc);
    }
    for (; i < e; ++i) {
        const int2 e0 = epack[i];
        acc = fmaf(pre[(size_t)e0.x * OUT_DIM + j], __int_as_float(e0.y), acc);
    }
    const float r = acc + bias[j];
    out[(size_t)v * OUT_DIM + j] = r > 0.0f ? r : 0.0f;
}

extern "C" void kernel_launch(void* const* d_in, const int* in_sizes, int n_in,
                              void* d_out, int out_size, void* d_ws, size_t ws_size,
                              hipStream_t stream) {
    const float* x    = (const float*)d_in[0];
    const int* rows   = (const int*)d_in[1];
    const int* cols   = (const int*)d_in[2];
    const float* vals = (const float*)d_in[3];
    const float* w    = (const float*)d_in[4];
    const float* bias = (const float*)d_in[5];
    float* out        = (float*)d_out;

    float* pre  = (float*)d_ws;                          // 25.6 MB
    int* deg    = (int*)(pre + (size_t)N_NODES * OUT_DIM);
    int* off    = deg + N_NODES;                         // N_NODES+2
    int* cursor = off + N_NODES + 2;
    int* bsum   = cursor + N_NODES;                      // 128
    int* boff   = bsum + 128;                            // 128
    int2* epack = (int2*)(boff + 128);                   // 10.24 MB, 8B-aligned

    hipMemsetAsync(deg, 0, N_NODES * sizeof(int), stream);

    gemm_kernel<<<(N_NODES + 63) / 64, 256, 0, stream>>>(x, w, pre);

    hist_kernel<<<625, 256, 0, stream>>>(rows, deg);
    scan1_kernel<<<NB1, 256, 0, stream>>>(deg, off, bsum);
    scan2_kernel<<<1, 128, 0, stream>>>(bsum, boff, off);
    scan3_kernel<<<(N_NODES + 255) / 256, 256, 0, stream>>>(off, boff, cursor);

    reorder_kernel<<<1250, 256, 0, stream>>>(rows, cols, vals, cursor, epack);

    gather_kernel<<<(N_NODES + 3) / 4, 256, 0, stream>>>(off, epack, pre, bias, out);
}

// Round 7
// 389.022 us; speedup vs baseline: 1.0697x; 1.0697x over previous
//
#include <hip/hip_runtime.h>
#include <hip/hip_bf16.h>
#include <stdint.h>

#define N_NODES 100000
#define N_EDGES 1280000
#define IN_DIM  256
#define OUT_DIM 64
#define NB1     98          // ceil(100000/1024) scan blocks
#define GEMM_BLOCKS ((N_NODES + 63) / 64)   // 1563

typedef __attribute__((ext_vector_type(8))) short bf16x8;
typedef __attribute__((ext_vector_type(4))) float f32x4;
typedef __attribute__((ext_vector_type(4))) unsigned short u16x4;

__device__ __forceinline__ unsigned short f32_to_bf16(float f) {
    union { float f; unsigned int u; } c; c.f = f;
    unsigned int u = c.u;
    u += 0x7fffu + ((u >> 16) & 1u);   // RNE
    return (unsigned short)(u >> 16);
}
__device__ __forceinline__ float bf16_to_f32(unsigned short h) {
    union { unsigned int u; float f; } c; c.u = ((unsigned int)h) << 16; return c.f;
}

// ---------------------------------------------------------------------------
// K1: GEMM (pre[N][64] bf16 = bf16(X)@bf16(W), MFMA 16x16x32) + hist tail.
// gemm part unchanged from round 5 (proven). After the C-store, each block
// processes a grid-stride slice of edges for the degree histogram —
// fire-and-forget atomics hidden under other blocks' gemm work.
// ---------------------------------------------------------------------------
__global__ __launch_bounds__(256) void gemm_hist_kernel(const float* __restrict__ x,
                                                        const float* __restrict__ w,
                                                        unsigned short* __restrict__ pre,
                                                        const int* __restrict__ rows,
                                                        int* __restrict__ deg) {
    __shared__ __align__(16) unsigned short wt[8 * 4 * 64 * 8];   // 32 KB, B-frag order
    __shared__ __align__(16) unsigned short xs[4][8][4][136];     // 34 KB, A-frag order

    const int tid = threadIdx.x;

    for (int i = tid; i < IN_DIM * OUT_DIM; i += 256) {
        const int k = i >> 6, n = i & 63;
        const int kt = k >> 5, q = (k >> 3) & 3, j = k & 7;
        const int t = n >> 4, l = n & 15;
        wt[((kt * 4 + t) * 64 + q * 16 + l) * 8 + j] = f32_to_bf16(w[i]);
    }

    const int R0 = blockIdx.x * 64;
    #pragma unroll
    for (int it = 0; it < 16; ++it) {
        const int flatv = it * 256 + tid;
        const int r  = flatv >> 6;
        const int k4 = (flatv & 63) * 4;
        int gr = R0 + r; gr = gr < N_NODES ? gr : N_NODES - 1;
        f32x4 xv = *(const f32x4*)(x + (size_t)gr * IN_DIM + k4);
        const int kt = k4 >> 5, q = (k4 >> 3) & 3, j = k4 & 7;
        u16x4 pk;
        pk[0] = f32_to_bf16(xv.x); pk[1] = f32_to_bf16(xv.y);
        pk[2] = f32_to_bf16(xv.z); pk[3] = f32_to_bf16(xv.w);
        *(u16x4*)&xs[r >> 4][kt][q][(r & 15) * 8 + j] = pk;
    }
    __syncthreads();

    const int wave = tid >> 6;
    const int lane = tid & 63;
    const int ln16 = lane & 15;
    const int quad = lane >> 4;

    f32x4 acc[4] = {};

    #pragma unroll
    for (int kt = 0; kt < 8; ++kt) {
        bf16x8 a = *(const bf16x8*)&xs[wave][kt][quad][ln16 * 8];
        #pragma unroll
        for (int t = 0; t < 4; ++t) {
            bf16x8 b = *(const bf16x8*)(&wt[((kt * 4 + t) * 64 + lane) * 8]);
            acc[t] = __builtin_amdgcn_mfma_f32_16x16x32_bf16(a, b, acc[t], 0, 0, 0);
        }
    }

    const int rbase = R0 + wave * 16 + quad * 4;
    #pragma unroll
    for (int t = 0; t < 4; ++t) {
        #pragma unroll
        for (int r = 0; r < 4; ++r) {
            const int rr = rbase + r;
            if (rr < N_NODES)
                pre[(size_t)rr * OUT_DIM + t * 16 + ln16] = f32_to_bf16(acc[t][r]);
        }
    }

    // ---- hist tail: grid-stride over edges, fire-and-forget atomics ----
    for (int e = blockIdx.x * 256 + tid; e < N_EDGES; e += GEMM_BLOCKS * 256) {
        atomicAdd(&deg[rows[e]], 1);
    }
}

__global__ __launch_bounds__(256) void scan1_kernel(const int* __restrict__ deg,
                                                    int* __restrict__ off,
                                                    int* __restrict__ bsum) {
    __shared__ int s[256];
    const int t = threadIdx.x;
    const int base = blockIdx.x * 1024 + t * 4;
    int d[4];
    #pragma unroll
    for (int q = 0; q < 4; ++q) {
        const int i = base + q;
        d[q] = i < N_NODES ? deg[i] : 0;
    }
    const int tsum = d[0] + d[1] + d[2] + d[3];
    s[t] = tsum;
    __syncthreads();
    #pragma unroll
    for (int o = 1; o < 256; o <<= 1) {
        const int add = t >= o ? s[t - o] : 0;
        __syncthreads();
        s[t] += add;
        __syncthreads();
    }
    int run = t > 0 ? s[t - 1] : 0;
    #pragma unroll
    for (int q = 0; q < 4; ++q) {
        const int i = base + q;
        if (i < N_NODES) off[i] = run;
        run += d[q];
    }
    if (t == 255) bsum[blockIdx.x] = run;
}

__global__ __launch_bounds__(128) void scan2_kernel(const int* __restrict__ bsum,
                                                    int* __restrict__ boff,
                                                    int* __restrict__ off) {
    __shared__ int s[128];
    const int t = threadIdx.x;
    const int v = t < NB1 ? bsum[t] : 0;
    s[t] = v;
    __syncthreads();
    #pragma unroll
    for (int o = 1; o < 128; o <<= 1) {
        const int add = t >= o ? s[t - o] : 0;
        __syncthreads();
        s[t] += add;
        __syncthreads();
    }
    if (t < NB1) boff[t] = t > 0 ? s[t - 1] : 0;
    if (t == 127) off[N_NODES] = s[127];
}

__global__ __launch_bounds__(256) void scan3_kernel(int* __restrict__ off,
                                                    const int* __restrict__ boff,
                                                    int* __restrict__ cursor) {
    const int i = blockIdx.x * 256 + threadIdx.x;
    if (i < N_NODES) {
        const int v = off[i] + boff[i >> 10];
        off[i] = v;
        cursor[i] = v;
    }
}

// ---------------------------------------------------------------------------
// Reorder: 1 edge/thread, 5000 blocks (max TLP — round-6 showed TLP >> ILP).
// Non-temporal 8B store for the random epack scatter (bypass write-allocate).
// ---------------------------------------------------------------------------
__global__ __launch_bounds__(256) void reorder_kernel(const int* __restrict__ rows,
                                                      const int* __restrict__ cols,
                                                      const float* __restrict__ vals,
                                                      int* __restrict__ cursor,
                                                      unsigned long long* __restrict__ epack) {
    const int e = blockIdx.x * 256 + threadIdx.x;
    if (e < N_EDGES) {
        const int r = rows[e];
        const int c = cols[e];
        const float v = vals[e];
        const int slot = atomicAdd(&cursor[r], 1);
        const unsigned long long pk =
            ((unsigned long long)__float_as_uint(v) << 32) | (unsigned int)c;
        __builtin_nontemporal_store(pk, &epack[slot]);
    }
}

// ---------------------------------------------------------------------------
// Gather: one wave per node, lane = dim, 4-deep ILP. pre is bf16 (128B/edge).
// Fused bias + ReLU. Zero atomics.
// ---------------------------------------------------------------------------
__global__ __launch_bounds__(256) void gather_kernel(const int* __restrict__ off,
                                                     const unsigned long long* __restrict__ epack,
                                                     const unsigned short* __restrict__ pre,
                                                     const float* __restrict__ bias,
                                                     float* __restrict__ out) {
    const int v = blockIdx.x * 4 + (threadIdx.x >> 6);
    const int j = threadIdx.x & 63;
    if (v >= N_NODES) return;
    const int s = off[v];
    const int e = off[v + 1];
    float acc = 0.0f;
    int i = s;
    for (; i + 4 <= e; i += 4) {
        unsigned long long ee[4];
        float p[4];
        #pragma unroll
        for (int q = 0; q < 4; ++q) ee[q] = epack[i + q];
        #pragma unroll
        for (int q = 0; q < 4; ++q)
            p[q] = bf16_to_f32(pre[(size_t)(unsigned int)(ee[q] & 0xffffffffu) * OUT_DIM + j]);
        #pragma unroll
        for (int q = 0; q < 4; ++q)
            acc = fmaf(p[q], __uint_as_float((unsigned int)(ee[q] >> 32)), acc);
    }
    for (; i < e; ++i) {
        const unsigned long long e0 = epack[i];
        acc = fmaf(bf16_to_f32(pre[(size_t)(unsigned int)(e0 & 0xffffffffu) * OUT_DIM + j]),
                   __uint_as_float((unsigned int)(e0 >> 32)), acc);
    }
    const float r = acc + bias[j];
    out[(size_t)v * OUT_DIM + j] = r > 0.0f ? r : 0.0f;
}

extern "C" void kernel_launch(void* const* d_in, const int* in_sizes, int n_in,
                              void* d_out, int out_size, void* d_ws, size_t ws_size,
                              hipStream_t stream) {
    const float* x    = (const float*)d_in[0];
    const int* rows   = (const int*)d_in[1];
    const int* cols   = (const int*)d_in[2];
    const float* vals = (const float*)d_in[3];
    const float* w    = (const float*)d_in[4];
    const float* bias = (const float*)d_in[5];
    float* out        = (float*)d_out;

    unsigned short* pre = (unsigned short*)d_ws;               // 12.8 MB bf16
    int* deg    = (int*)(pre + (size_t)N_NODES * OUT_DIM);
    int* off    = deg + N_NODES;                               // N_NODES+2
    int* cursor = off + N_NODES + 2;
    int* bsum   = cursor + N_NODES;                            // 128
    int* boff   = bsum + 128;                                  // 128
    unsigned long long* epack = (unsigned long long*)(boff + 128); // 10.24 MB, 8B-aligned

    hipMemsetAsync(deg, 0, N_NODES * sizeof(int), stream);

    gemm_hist_kernel<<<GEMM_BLOCKS, 256, 0, stream>>>(x, w, pre, rows, deg);

    scan1_kernel<<<NB1, 256, 0, stream>>>(deg, off, bsum);
    scan2_kernel<<<1, 128, 0, stream>>>(bsum, boff, off);
    scan3_kernel<<<(N_NODES + 255) / 256, 256, 0, stream>>>(off, boff, cursor);

    reorder_kernel<<<(N_EDGES + 255) / 256, 256, 0, stream>>>(rows, cols, vals, cursor, epack);

    gather_kernel<<<(N_NODES + 3) / 4, 256, 0, stream>>>(off, epack, pre, bias, out);
}

// Round 8
// 343.845 us; speedup vs baseline: 1.2103x; 1.1314x over previous
//
#include <hip/hip_runtime.h>
#include <hip/hip_bf16.h>
#include <stdint.h>

#define N_NODES 100000
#define N_EDGES 1280000
#define IN_DIM  256
#define OUT_DIM 64
#define NB1     98          // ceil(100000/1024) scan blocks
#define GEMM_BLOCKS ((N_NODES + 63) / 64)   // 1563
#define PART_SZ 12500       // nodes per XCD partition (100000/8)

typedef __attribute__((ext_vector_type(8))) short bf16x8;
typedef __attribute__((ext_vector_type(4))) float f32x4;
typedef __attribute__((ext_vector_type(4))) unsigned short u16x4;

__device__ __forceinline__ unsigned short f32_to_bf16(float f) {
    union { float f; unsigned int u; } c; c.f = f;
    unsigned int u = c.u;
    u += 0x7fffu + ((u >> 16) & 1u);   // RNE
    return (unsigned short)(u >> 16);
}
__device__ __forceinline__ float bf16_to_f32(unsigned short h) {
    union { unsigned int u; float f; } c; c.u = ((unsigned int)h) << 16; return c.f;
}

// ---------------------------------------------------------------------------
// K1: GEMM (pre[N][64] bf16 = bf16(X)@bf16(W), MFMA 16x16x32) + hist tail.
// (unchanged from round 7 — proven)
// ---------------------------------------------------------------------------
__global__ __launch_bounds__(256) void gemm_hist_kernel(const float* __restrict__ x,
                                                        const float* __restrict__ w,
                                                        unsigned short* __restrict__ pre,
                                                        const int* __restrict__ rows,
                                                        int* __restrict__ deg) {
    __shared__ __align__(16) unsigned short wt[8 * 4 * 64 * 8];   // 32 KB, B-frag order
    __shared__ __align__(16) unsigned short xs[4][8][4][136];     // 34 KB, A-frag order

    const int tid = threadIdx.x;

    for (int i = tid; i < IN_DIM * OUT_DIM; i += 256) {
        const int k = i >> 6, n = i & 63;
        const int kt = k >> 5, q = (k >> 3) & 3, j = k & 7;
        const int t = n >> 4, l = n & 15;
        wt[((kt * 4 + t) * 64 + q * 16 + l) * 8 + j] = f32_to_bf16(w[i]);
    }

    const int R0 = blockIdx.x * 64;
    #pragma unroll
    for (int it = 0; it < 16; ++it) {
        const int flatv = it * 256 + tid;
        const int r  = flatv >> 6;
        const int k4 = (flatv & 63) * 4;
        int gr = R0 + r; gr = gr < N_NODES ? gr : N_NODES - 1;
        f32x4 xv = *(const f32x4*)(x + (size_t)gr * IN_DIM + k4);
        const int kt = k4 >> 5, q = (k4 >> 3) & 3, j = k4 & 7;
        u16x4 pk;
        pk[0] = f32_to_bf16(xv.x); pk[1] = f32_to_bf16(xv.y);
        pk[2] = f32_to_bf16(xv.z); pk[3] = f32_to_bf16(xv.w);
        *(u16x4*)&xs[r >> 4][kt][q][(r & 15) * 8 + j] = pk;
    }
    __syncthreads();

    const int wave = tid >> 6;
    const int lane = tid & 63;
    const int ln16 = lane & 15;
    const int quad = lane >> 4;

    f32x4 acc[4] = {};

    #pragma unroll
    for (int kt = 0; kt < 8; ++kt) {
        bf16x8 a = *(const bf16x8*)&xs[wave][kt][quad][ln16 * 8];
        #pragma unroll
        for (int t = 0; t < 4; ++t) {
            bf16x8 b = *(const bf16x8*)(&wt[((kt * 4 + t) * 64 + lane) * 8]);
            acc[t] = __builtin_amdgcn_mfma_f32_16x16x32_bf16(a, b, acc[t], 0, 0, 0);
        }
    }

    const int rbase = R0 + wave * 16 + quad * 4;
    #pragma unroll
    for (int t = 0; t < 4; ++t) {
        #pragma unroll
        for (int r = 0; r < 4; ++r) {
            const int rr = rbase + r;
            if (rr < N_NODES)
                pre[(size_t)rr * OUT_DIM + t * 16 + ln16] = f32_to_bf16(acc[t][r]);
        }
    }

    // ---- hist tail: grid-stride over edges, fire-and-forget atomics ----
    for (int e = blockIdx.x * 256 + tid; e < N_EDGES; e += GEMM_BLOCKS * 256) {
        atomicAdd(&deg[rows[e]], 1);
    }
}

__global__ __launch_bounds__(256) void scan1_kernel(const int* __restrict__ deg,
                                                    int* __restrict__ off,
                                                    int* __restrict__ bsum) {
    __shared__ int s[256];
    const int t = threadIdx.x;
    const int base = blockIdx.x * 1024 + t * 4;
    int d[4];
    #pragma unroll
    for (int q = 0; q < 4; ++q) {
        const int i = base + q;
        d[q] = i < N_NODES ? deg[i] : 0;
    }
    const int tsum = d[0] + d[1] + d[2] + d[3];
    s[t] = tsum;
    __syncthreads();
    #pragma unroll
    for (int o = 1; o < 256; o <<= 1) {
        const int add = t >= o ? s[t - o] : 0;
        __syncthreads();
        s[t] += add;
        __syncthreads();
    }
    int run = t > 0 ? s[t - 1] : 0;
    #pragma unroll
    for (int q = 0; q < 4; ++q) {
        const int i = base + q;
        if (i < N_NODES) off[i] = run;
        run += d[q];
    }
    if (t == 255) bsum[blockIdx.x] = run;
}

__global__ __launch_bounds__(128) void scan2_kernel(const int* __restrict__ bsum,
                                                    int* __restrict__ boff,
                                                    int* __restrict__ off) {
    __shared__ int s[128];
    const int t = threadIdx.x;
    const int v = t < NB1 ? bsum[t] : 0;
    s[t] = v;
    __syncthreads();
    #pragma unroll
    for (int o = 1; o < 128; o <<= 1) {
        const int add = t >= o ? s[t - o] : 0;
        __syncthreads();
        s[t] += add;
        __syncthreads();
    }
    if (t < NB1) boff[t] = t > 0 ? s[t - 1] : 0;
    if (t == 127) off[N_NODES] = s[127];
}

__global__ __launch_bounds__(256) void scan3_kernel(int* __restrict__ off,
                                                    const int* __restrict__ boff,
                                                    int* __restrict__ cursor) {
    const int i = blockIdx.x * 256 + threadIdx.x;
    if (i < N_NODES) {
        const int v = off[i] + boff[i >> 10];
        off[i] = v;
        cursor[i] = v;
    }
}

// ---------------------------------------------------------------------------
// Reorder, XCD-partitioned: block g covers edge-chunk (g>>3) but only commits
// edges whose destination row lies in node-partition (g&7). With round-robin
// block->XCD dispatch, all stores for a node's slot range issue from ONE XCD,
// so its L2 coalesces the ~12.8 consecutive 8B writes per node into whole
// lines (round-7 showed 8x write amplification from cross-XCD partial lines).
// 5000 blocks: 625 chunks x 8 partitions; chunk = 2048 edges.
// ---------------------------------------------------------------------------
__global__ __launch_bounds__(256) void reorder_kernel(const int* __restrict__ rows,
                                                      const int* __restrict__ cols,
                                                      const float* __restrict__ vals,
                                                      int* __restrict__ cursor,
                                                      unsigned long long* __restrict__ epack) {
    const int part = blockIdx.x & 7;
    const int lo = part * PART_SZ;
    const int hi = lo + PART_SZ;            // partition 7: 87500..100000
    const int base = (blockIdx.x >> 3) * 2048 + threadIdx.x;
    #pragma unroll
    for (int k = 0; k < 8; ++k) {
        const int e = base + k * 256;
        const int r = rows[e];
        if (r >= lo && r < hi) {
            const int c = cols[e];
            const float v = vals[e];
            const int slot = atomicAdd(&cursor[r], 1);
            epack[slot] = ((unsigned long long)__float_as_uint(v) << 32) | (unsigned int)c;
        }
    }
}

// ---------------------------------------------------------------------------
// Gather: one wave per node, lane = dim, 4-deep ILP. pre is bf16 (128B/edge).
// Fused bias + ReLU. Zero atomics.
// ---------------------------------------------------------------------------
__global__ __launch_bounds__(256) void gather_kernel(const int* __restrict__ off,
                                                     const unsigned long long* __restrict__ epack,
                                                     const unsigned short* __restrict__ pre,
                                                     const float* __restrict__ bias,
                                                     float* __restrict__ out) {
    const int v = blockIdx.x * 4 + (threadIdx.x >> 6);
    const int j = threadIdx.x & 63;
    if (v >= N_NODES) return;
    const int s = off[v];
    const int e = off[v + 1];
    float acc = 0.0f;
    int i = s;
    for (; i + 4 <= e; i += 4) {
        unsigned long long ee[4];
        float p[4];
        #pragma unroll
        for (int q = 0; q < 4; ++q) ee[q] = epack[i + q];
        #pragma unroll
        for (int q = 0; q < 4; ++q)
            p[q] = bf16_to_f32(pre[(size_t)(unsigned int)(ee[q] & 0xffffffffu) * OUT_DIM + j]);
        #pragma unroll
        for (int q = 0; q < 4; ++q)
            acc = fmaf(p[q], __uint_as_float((unsigned int)(ee[q] >> 32)), acc);
    }
    for (; i < e; ++i) {
        const unsigned long long e0 = epack[i];
        acc = fmaf(bf16_to_f32(pre[(size_t)(unsigned int)(e0 & 0xffffffffu) * OUT_DIM + j]),
                   __uint_as_float((unsigned int)(e0 >> 32)), acc);
    }
    const float r = acc + bias[j];
    out[(size_t)v * OUT_DIM + j] = r > 0.0f ? r : 0.0f;
}

extern "C" void kernel_launch(void* const* d_in, const int* in_sizes, int n_in,
                              void* d_out, int out_size, void* d_ws, size_t ws_size,
                              hipStream_t stream) {
    const float* x    = (const float*)d_in[0];
    const int* rows   = (const int*)d_in[1];
    const int* cols   = (const int*)d_in[2];
    const float* vals = (const float*)d_in[3];
    const float* w    = (const float*)d_in[4];
    const float* bias = (const float*)d_in[5];
    float* out        = (float*)d_out;

    unsigned short* pre = (unsigned short*)d_ws;               // 12.8 MB bf16
    int* deg    = (int*)(pre + (size_t)N_NODES * OUT_DIM);
    int* off    = deg + N_NODES;                               // N_NODES+2
    int* cursor = off + N_NODES + 2;
    int* bsum   = cursor + N_NODES;                            // 128
    int* boff   = bsum + 128;                                  // 128
    unsigned long long* epack = (unsigned long long*)(boff + 128); // 10.24 MB, 8B-aligned

    hipMemsetAsync(deg, 0, N_NODES * sizeof(int), stream);

    gemm_hist_kernel<<<GEMM_BLOCKS, 256, 0, stream>>>(x, w, pre, rows, deg);

    scan1_kernel<<<NB1, 256, 0, stream>>>(deg, off, bsum);
    scan2_kernel<<<1, 128, 0, stream>>>(bsum, boff, off);
    scan3_kernel<<<(N_NODES + 255) / 256, 256, 0, stream>>>(off, boff, cursor);

    reorder_kernel<<<5000, 256, 0, stream>>>(rows, cols, vals, cursor, epack);

    gather_kernel<<<(N_NODES + 3) / 4, 256, 0, stream>>>(off, epack, pre, bias, out);
}